// Round 5
// baseline (1996.305 us; speedup 1.0000x reference)
//
#include <hip/hip_runtime.h>
#include <hip/hip_bf16.h>

typedef __attribute__((ext_vector_type(8))) short bf16x8;
typedef __attribute__((ext_vector_type(4))) float f32x4;

#define B_   64
#define S_   512
#define M_   32768
#define D_   256

__device__ __forceinline__ float b2f(unsigned short u) {
    union { unsigned int i; float f; } v; v.i = ((unsigned int)u) << 16; return v.f;
}
__device__ __forceinline__ unsigned short f2b(float f) {
    union { float f; unsigned int i; } v; v.f = f;
    unsigned int x = v.i;
    return (unsigned short)((x + 0x7fffu + ((x >> 16) & 1u)) >> 16);
}
__device__ __forceinline__ float sigm(float x) { return 1.f / (1.f + __expf(-x)); }

__device__ __forceinline__ float ldany(const void* p, size_t i, int f32) {
    return f32 ? ((const float*)p)[i] : b2f(((const unsigned short*)p)[i]);
}

// output-channel interleave map: o in [0,512) -> packed n
__device__ __forceinline__ int omap(int o) {
    int half = o >> 8, d = o & 255;
    return ((d >> 4) * 32) + half * 16 + (d & 15);
}
// inverse: n -> o
__device__ __forceinline__ int omap_inv(int n) {
    int grp = n >> 5, half = (n >> 4) & 1, dlow = n & 15;
    return half * 256 + grp * 16 + dlow;
}

// ---------------------------------------------------------------- dtype detect
__global__ void k_detect(const void* sample, int* flag) {
    __shared__ int s;
    int t = threadIdx.x;
    if (t == 0) s = 0;
    __syncthreads();
    const unsigned short* u = (const unsigned short*)sample;
    float a = fabsf(b2f(u[2 * t]));
    if (!(a < 1e3f)) atomicOr(&s, 1);
    __syncthreads();
    if (t == 0) *flag = s;
}

// ---------------------------------------------------------------- embed + mask
__global__ __launch_bounds__(256)
void k_embed(const int* __restrict__ ids_c, const int* __restrict__ ids_w,
             const int* __restrict__ ids_p,
             const void* __restrict__ char_t,
             const void* __restrict__ word_t,
             const void* __restrict__ pos_t,
             unsigned short* __restrict__ embed,
             float* __restrict__ maskf,
             void* __restrict__ outv,
             const int* __restrict__ flag) {
    const int f32 = *flag;
    const int t = threadIdx.x;
    const int pos = blockIdx.x * 4 + (t >> 6);
    const int ch0 = (t & 63) * 8;
    const int c = ids_c[pos], w = ids_w[pos], p = ids_p[pos];
    if ((t & 63) == 0) {
        float m = (c != 0) ? 1.f : 0.f;
        maskf[pos] = m;
        size_t eidx = 65536 + 3276800 + (size_t)pos;
        if (f32) ((float*)outv)[eidx] = m;
        else ((unsigned short*)outv)[eidx] = f2b(m);
    }
    float tab[8], pe[8];
    const int in_char = (ch0 < 256);
    const size_t tidx = in_char ? ((size_t)c * 256 + ch0) : ((size_t)w * 256 + (ch0 - 256));
    const void* tp = in_char ? char_t : word_t;
    if (f32) {
        const float4 a0 = *(const float4*)((const float*)tp + tidx);
        const float4 a1 = *(const float4*)((const float*)tp + tidx + 4);
        tab[0]=a0.x; tab[1]=a0.y; tab[2]=a0.z; tab[3]=a0.w;
        tab[4]=a1.x; tab[5]=a1.y; tab[6]=a1.z; tab[7]=a1.w;
        const float4 b0 = *(const float4*)((const float*)pos_t + (size_t)p * 512 + ch0);
        const float4 b1 = *(const float4*)((const float*)pos_t + (size_t)p * 512 + ch0 + 4);
        pe[0]=b0.x; pe[1]=b0.y; pe[2]=b0.z; pe[3]=b0.w;
        pe[4]=b1.x; pe[5]=b1.y; pe[6]=b1.z; pe[7]=b1.w;
    } else {
        const unsigned short* tu = (const unsigned short*)tp + tidx;
        const unsigned short* pu = (const unsigned short*)pos_t + (size_t)p * 512 + ch0;
        uint4 av = *(const uint4*)tu;
        uint4 bv = *(const uint4*)pu;
        const unsigned short* as = (const unsigned short*)&av;
        const unsigned short* bs = (const unsigned short*)&bv;
#pragma unroll
        for (int i = 0; i < 8; ++i) { tab[i] = b2f(as[i]); pe[i] = b2f(bs[i]); }
    }
    unsigned short o[8];
#pragma unroll
    for (int i = 0; i < 8; ++i) o[i] = f2b(tab[i] + pe[i]);
    *(uint4*)(embed + (size_t)pos * 512 + ch0) = *(uint4*)o;
}

// ---------------------------------------------------------------- weight repack
__global__ void k_repack(const void* __restrict__ w1,
                         const void* __restrict__ w11,
                         const void* __restrict__ b1,
                         const void* __restrict__ b11,
                         unsigned short* __restrict__ w1p,
                         unsigned short* __restrict__ wp,
                         float* __restrict__ biasP,
                         const int* __restrict__ flag) {
    const int f32 = *flag;
    const int T1 = 3 * 512 * 512 / 8;
    const int T2 = 11 * 3 * 512 * 256 / 8;
    const int T3 = 12 * 512;
    const int total = T1 + T2 + T3;
    for (int idx = blockIdx.x * blockDim.x + threadIdx.x; idx < total;
         idx += gridDim.x * blockDim.x) {
        if (idx < T1) {
            int row = idx >> 6;
            int c0 = (idx & 63) * 8;
            int tap = row >> 9, n = row & 511;
            int o = omap_inv(n);
            unsigned short v[8];
#pragma unroll
            for (int i = 0; i < 8; ++i)
                v[i] = f2b(ldany(w1, (size_t)tap * 262144 + (size_t)(c0 + i) * 512 + o, f32));
            *(uint4*)(w1p + ((size_t)row << 9) + c0) = *(uint4*)v;
        } else if (idx < T1 + T2) {
            int j = idx - T1;
            int row = j >> 5;
            int c0 = (j & 31) * 8;
            int lt = row >> 9, n = row & 511;
            int o = omap_inv(n);
            unsigned short v[8];
#pragma unroll
            for (int i = 0; i < 8; ++i)
                v[i] = f2b(ldany(w11, (size_t)lt * 131072 + (size_t)(c0 + i) * 512 + o, f32));
            *(uint4*)(wp + ((size_t)row << 8) + c0) = *(uint4*)v;
        } else {
            int j = idx - T1 - T2;
            if (j < 512) {
                biasP[omap(j)] = ldany(b1, j, f32);
            } else {
                int jj = j - 512;
                int lay = jj >> 9, o = jj & 511;
                biasP[512 + lay * 512 + omap(o)] = ldany(b11, jj, f32);
            }
        }
    }
}

// ---------------------------------------------------------------- gated dilated conv layer
// K-loop: 2 barriers per k0 (BK=64), all 3 taps' B in LDS (XOR-swizzled,
// conflict-free), next-k0 B prefetched into regs during MFMA, A fragments
// read direct from global (L1/L2-resident; per-lane boundary predicate).
template <int CIN, bool RES>
__global__ __launch_bounds__(256, 3)
void k_dgc(const unsigned short* __restrict__ xin,
           const unsigned short* __restrict__ wT,
           const float* __restrict__ bias,
           const float* __restrict__ maskf,
           unsigned short* __restrict__ xout,
           int dil) {
    __shared__ unsigned short ldsB[3 * 128 * 64];   // 49152 B -> 3 blocks/CU
    const int id = blockIdx.x;
    const int xcd = id & 7, sl = id >> 3;
    const int mt = xcd * 32 + (sl >> 2);            // same-mt blocks share an XCD
    const int nt = sl & 3;
    const int m0 = mt * 128, n0 = nt * 128;
    const int b = m0 >> 9, s0 = m0 & 511;
    const int t = threadIdx.x;
    const int lane = t & 63, wv = t >> 6;
    const int wm = wv >> 1, wn = wv & 1;
    const int lm = lane & 15, lq = lane >> 4;

    // B staging plan: 3072 uint4 chunks, 12 per thread; LDS offsets are
    // k0-invariant, global pointers advance by k0.
    int bls[12];
    const unsigned short* bgp[12];
#pragma unroll
    for (int i0 = 0; i0 < 12; ++i0) {
        int i = t + i0 * 256;
        int tap = i >> 10, rem = i & 1023;
        int row = rem >> 3, q = rem & 7;
        bls[i0] = (tap * 128 + row) * 64 + ((q ^ (row & 7)) * 8);
        bgp[i0] = wT + ((size_t)tap * 512 + n0 + row) * CIN + q * 8;
    }

    f32x4 acc[4][4];
#pragma unroll
    for (int i = 0; i < 4; i++)
#pragma unroll
        for (int j = 0; j < 4; j++)
#pragma unroll
            for (int e = 0; e < 4; e++) acc[i][j][e] = 0.f;

    uint4 pB[12];
#pragma unroll
    for (int i0 = 0; i0 < 12; ++i0) pB[i0] = *(const uint4*)(bgp[i0]);

    const unsigned short* xrow = xin + (size_t)b * S_ * CIN;

    for (int k0 = 0; k0 < CIN; k0 += 64) {
        __syncthreads();
#pragma unroll
        for (int i0 = 0; i0 < 12; ++i0)
            *(uint4*)(ldsB + bls[i0]) = pB[i0];
        __syncthreads();
        if (k0 + 64 < CIN) {
#pragma unroll
            for (int i0 = 0; i0 < 12; ++i0)
                pB[i0] = *(const uint4*)(bgp[i0] + k0 + 64);
        }
#pragma unroll
        for (int tap = 0; tap < 3; ++tap) {
            const int roff = (tap - 1) * dil;
#pragma unroll
            for (int kk = 0; kk < 2; ++kk) {
                bf16x8 af[4], bfr[4];
#pragma unroll
                for (int mi = 0; mi < 4; ++mi) {
                    const int sp = s0 + wm * 64 + mi * 16 + lm + roff;
                    bf16x8 z = {0, 0, 0, 0, 0, 0, 0, 0};
                    if (sp >= 0 && sp < S_)
                        z = *(const bf16x8*)(xrow + (size_t)sp * CIN + k0 + kk * 32 + lq * 8);
                    af[mi] = z;
                }
#pragma unroll
                for (int ni = 0; ni < 4; ++ni) {
                    const int br = wn * 64 + ni * 16 + lm;
                    bfr[ni] = *(const bf16x8*)(ldsB + (tap * 128 + br) * 64 +
                                               (((kk * 4 + lq) ^ (br & 7)) * 8));
                }
#pragma unroll
                for (int mi = 0; mi < 4; ++mi)
#pragma unroll
                    for (int ni = 0; ni < 4; ++ni)
                        acc[mi][ni] = __builtin_amdgcn_mfma_f32_16x16x32_bf16(
                            af[mi], bfr[ni], acc[mi][ni], 0, 0, 0);
            }
        }
    }

    // epilogue: ni pairs (2p, 2p+1) = (gate, value) blocks of same d-group
    const int colbase = n0 + wn * 64;
#pragma unroll
    for (int mi = 0; mi < 4; ++mi) {
#pragma unroll
        for (int p = 0; p < 2; ++p) {
            const int d = (colbase >> 1) + p * 16 + lm;
            const int ng = colbase + p * 32 + lm;
            const float bg = bias[ng], bv = bias[ng + 16];
#pragma unroll
            for (int r = 0; r < 4; ++r) {
                const int m = m0 + wm * 64 + mi * 16 + lq * 4 + r;
                float hg = acc[mi][2 * p][r] + bg;
                float hv = acc[mi][2 * p + 1][r] + bv;
                float g = sigm(hg);
                float o = hv * g;
                if (RES) {
                    float xi = b2f(xin[(size_t)m * CIN + d]);
                    o = xi * (1.f - g) + hv * g;
                }
                o *= maskf[m];
                xout[(size_t)m * 256 + d] = f2b(o);
            }
        }
    }
}

// ---------------------------------------------------------------- gather vec
__global__ void k_vec(const unsigned short* __restrict__ x, const int* __restrict__ loc,
                      float* __restrict__ vec) {
    int b = blockIdx.x;
    int j = threadIdx.x;
    int which = j >> 8, d = j & 255;
    int s = loc[b * 2 + which];
    vec[b * 512 + j] = b2f(x[((size_t)(b * 512 + s)) * 256 + d]);
}

// ---------------------------------------------------------------- BN stats over x
__global__ void k_zero(float* __restrict__ stats) { stats[threadIdx.x] = 0.f; }

__global__ void k_stats(const unsigned short* __restrict__ x, float* __restrict__ stats) {
    int c = threadIdx.x;
    int base = blockIdx.x * 128;
    float s = 0.f, q = 0.f;
    for (int r = 0; r < 128; ++r) {
        float v = b2f(x[(size_t)(base + r) * 256 + c]);
        s += v; q += v * v;
    }
    atomicAdd(&stats[c], s);
    atomicAdd(&stats[256 + c], q);
}

// ---------------------------------------------------------------- BN scale/shift
__global__ void k_final(const float* __restrict__ stats, const float* __restrict__ vec,
                        const void* __restrict__ gamma,
                        const void* __restrict__ beta,
                        float* __restrict__ scale, float* __restrict__ shift,
                        const int* __restrict__ flag) {
    const int f32 = *flag;
    int f = threadIdx.x;
    float mu, var;
    if (f < 256) {
        mu = stats[f] * (1.f / 32768.f);
        var = stats[256 + f] * (1.f / 32768.f) - mu * mu;
    } else {
        float s = 0.f, q = 0.f;
        int j = f - 256;
        for (int b = 0; b < 64; ++b) {
            float v = vec[b * 512 + j];
            s += v; q += v * v;
        }
        mu = s * (1.f / 64.f);
        var = q * (1.f / 64.f) - mu * mu;
    }
    float sc = ldany(gamma, f, f32) * rsqrtf(var + 1e-3f);
    scale[f] = sc;
    shift[f] = ldany(beta, f, f32) - mu * sc;
}

// ---------------------------------------------------------------- projection weight prep
__global__ void k_prep1(const float* __restrict__ scale, const void* __restrict__ po_w,
                        const void* __restrict__ sub_w,
                        unsigned short* __restrict__ pwT,
                        const int* __restrict__ flag) {
    const int f32 = *flag;
    int idx = blockIdx.x * blockDim.x + threadIdx.x;
    int n = idx >> 8, k = idx & 255;
    float v = 0.f;
    if (n < 100) v = scale[k] * ldany(po_w, (size_t)k * 100 + n, f32);
    else if (n < 102) v = ldany(sub_w, (size_t)k * 2 + (n - 100), f32);
    pwT[n * 256 + k] = f2b(v);
}

// ---------------------------------------------------------------- Cmat: wave-per-(b,n)
__global__ __launch_bounds__(256)
void k_cmat(const float* __restrict__ scale, const float* __restrict__ shift,
            const float* __restrict__ vec,
            const void* __restrict__ po_w,
            const void* __restrict__ po_b,
            const void* __restrict__ sub_b,
            float* __restrict__ Cmat,
            const int* __restrict__ flag) {
    const int f32 = *flag;
    const int wid = blockIdx.x * 4 + (threadIdx.x >> 6);
    const int lane = threadIdx.x & 63;
    const int b = wid / 102, n = wid - b * 102;
    if (b >= 64) return;
    if (n >= 100) {
        if (lane == 0) Cmat[b * 128 + n] = ldany(sub_b, n - 100, f32);
        return;
    }
    float partial = 0.f;
#pragma unroll
    for (int f = lane; f < 768; f += 64) {
        float term = shift[f];
        if (f >= 256) term += vec[b * 512 + (f - 256)] * scale[f];
        partial += term * ldany(po_w, (size_t)f * 100 + n, f32);
    }
#pragma unroll
    for (int off = 32; off > 0; off >>= 1)
        partial += __shfl_xor(partial, off);
    if (lane == 0) Cmat[b * 128 + n] = partial + ldany(po_b, n, f32);
}

// ---------------------------------------------------------------- final GEMM
__global__ __launch_bounds__(256)
void k_po(const unsigned short* __restrict__ x,
          const unsigned short* __restrict__ pwT,
          const float* __restrict__ Cmat,
          void* __restrict__ outv,
          const int* __restrict__ flag) {
    const int f32 = *flag;
    __shared__ unsigned short ldsA[128 * 40];
    __shared__ unsigned short ldsB[128 * 40];
    const int mt = blockIdx.x;
    const int m0 = mt * 128;
    const int b = m0 >> 9;
    const int t = threadIdx.x;
    const int lane = t & 63, wv = t >> 6;
    const int wm = wv >> 1, wn = wv & 1;
    const int lm = lane & 15, lq = lane >> 4;

    f32x4 acc[4][4];
#pragma unroll
    for (int i = 0; i < 4; i++)
#pragma unroll
        for (int j = 0; j < 4; j++)
#pragma unroll
            for (int e = 0; e < 4; e++) acc[i][j][e] = 0.f;

    for (int k0 = 0; k0 < 256; k0 += 32) {
        __syncthreads();
#pragma unroll
        for (int a0 = 0; a0 < 2; ++a0) {
            int a = t + a0 * 256;
            int row = a >> 2, q = a & 3;
            uint4 va = *(const uint4*)(x + (size_t)(m0 + row) * 256 + k0 + q * 8);
            *(uint4*)(ldsA + row * 40 + q * 8) = va;
            uint4 vb = *(const uint4*)(pwT + (size_t)row * 256 + k0 + q * 8);
            *(uint4*)(ldsB + row * 40 + q * 8) = vb;
        }
        __syncthreads();
        bf16x8 af[4], bfr[4];
#pragma unroll
        for (int mi = 0; mi < 4; ++mi)
            af[mi] = *(const bf16x8*)(ldsA + (wm * 64 + mi * 16 + lm) * 40 + lq * 8);
#pragma unroll
        for (int ni = 0; ni < 4; ++ni)
            bfr[ni] = *(const bf16x8*)(ldsB + (wn * 64 + ni * 16 + lm) * 40 + lq * 8);
#pragma unroll
        for (int mi = 0; mi < 4; ++mi)
#pragma unroll
            for (int ni = 0; ni < 4; ++ni)
                acc[mi][ni] = __builtin_amdgcn_mfma_f32_16x16x32_bf16(
                    af[mi], bfr[ni], acc[mi][ni], 0, 0, 0);
    }

#pragma unroll
    for (int mi = 0; mi < 4; ++mi)
#pragma unroll
        for (int ni = 0; ni < 4; ++ni) {
            const int n = wn * 64 + ni * 16 + lm;
            const float cc = Cmat[b * 128 + n];
#pragma unroll
            for (int r = 0; r < 4; ++r) {
                const int m = m0 + wm * 64 + mi * 16 + lq * 4 + r;
                const int s = m & 511;
                float v = sigm(acc[mi][ni][r] + cc);
                if (n < 102) {
                    size_t eidx;
                    if (n < 100) eidx = 65536 + (((size_t)b * 100 + n) * 512 + s);
                    else eidx = ((size_t)b * 2 + (n - 100)) * 512 + s;
                    if (f32) ((float*)outv)[eidx] = v;
                    else ((unsigned short*)outv)[eidx] = f2b(v);
                }
            }
        }
}

// ---------------------------------------------------------------- launch
extern "C" void kernel_launch(void* const* d_in, const int* in_sizes, int n_in,
                              void* d_out, int out_size, void* d_ws, size_t ws_size,
                              hipStream_t stream) {
    const int* ids_c = (const int*)d_in[0];
    const int* ids_w = (const int*)d_in[1];
    const int* ids_p = (const int*)d_in[2];
    const int* loc = (const int*)d_in[3];
    const void* char_t = d_in[4];
    const void* word_t = d_in[5];
    const void* pos_t = d_in[6];
    const void* w1 = d_in[7];
    const void* b1 = d_in[8];
    const void* w11 = d_in[9];
    const void* b11 = d_in[10];
    const void* sub_w = d_in[11];
    const void* sub_b = d_in[12];
    const void* po_w = d_in[13];
    const void* po_b = d_in[14];
    const void* gamma = d_in[15];
    const void* beta = d_in[16];

    char* ws = (char*)d_ws;
    unsigned short* embed = (unsigned short*)(ws + 0);
    unsigned short* xA = (unsigned short*)(ws + 33554432);
    unsigned short* xB = (unsigned short*)(ws + 50331648);
    unsigned short* w1p = (unsigned short*)(ws + 67108864);
    unsigned short* wp = (unsigned short*)(ws + 68681728);
    float* biasP = (float*)(ws + 77332480);
    float* maskf = (float*)(ws + 77357056);
    float* vec = (float*)(ws + 77488128);
    float* stats = (float*)(ws + 77619200);
    float* scale = (float*)(ws + 77621248);
    float* shift = (float*)(ws + 77624320);
    unsigned short* pwT = (unsigned short*)(ws + 77627392);
    float* Cmat = (float*)(ws + 77692928);
    int* dflag = (int*)(ws + 77725696);

    k_detect<<<1, 256, 0, stream>>>(word_t, dflag);
    k_zero<<<1, 512, 0, stream>>>(stats);
    k_embed<<<8192, 256, 0, stream>>>(ids_c, ids_w, ids_p, char_t, word_t, pos_t,
                                      embed, maskf, d_out, dflag);
    k_repack<<<2560, 256, 0, stream>>>(w1, w11, b1, b11, w1p, wp, biasP, dflag);

    k_dgc<512, false><<<1024, 256, 0, stream>>>(embed, w1p, biasP, maskf, xA, 1);

    const int dils[12] = {1, 2, 5, 1, 2, 5, 1, 2, 5, 1, 1, 1};
    unsigned short* xi = xA;
    unsigned short* xo = xB;
    for (int i = 1; i < 12; ++i) {
        k_dgc<256, true><<<1024, 256, 0, stream>>>(
            xi, wp + (size_t)(i - 1) * 3 * 512 * 256, biasP + i * 512, maskf, xo, dils[i]);
        unsigned short* tmp = xi; xi = xo; xo = tmp;
    }

    k_vec<<<64, 512, 0, stream>>>(xi, loc, vec);
    k_stats<<<256, 256, 0, stream>>>(xi, stats);
    k_final<<<1, 768, 0, stream>>>(stats, vec, gamma, beta, scale, shift, dflag);
    k_prep1<<<128, 256, 0, stream>>>(scale, po_w, sub_w, pwT, dflag);
    k_cmat<<<1632, 256, 0, stream>>>(scale, shift, vec, po_w, po_b, sub_b, Cmat, dflag);
    k_po<<<256, 256, 0, stream>>>(xi, pwT, Cmat, d_out, dflag);
}

// Round 6
// 670.739 us; speedup vs baseline: 2.9763x; 2.9763x over previous
//
#include <hip/hip_runtime.h>
#include <hip/hip_bf16.h>

typedef __attribute__((ext_vector_type(8))) short bf16x8;
typedef __attribute__((ext_vector_type(4))) float f32x4;

#define B_   64
#define S_   512
#define M_   32768
#define D_   256

__device__ __forceinline__ float b2f(unsigned short u) {
    union { unsigned int i; float f; } v; v.i = ((unsigned int)u) << 16; return v.f;
}
__device__ __forceinline__ unsigned short f2b(float f) {
    union { float f; unsigned int i; } v; v.f = f;
    unsigned int x = v.i;
    return (unsigned short)((x + 0x7fffu + ((x >> 16) & 1u)) >> 16);
}
__device__ __forceinline__ float sigm(float x) { return 1.f / (1.f + __expf(-x)); }

__device__ __forceinline__ float ldany(const void* p, size_t i, int f32) {
    return f32 ? ((const float*)p)[i] : b2f(((const unsigned short*)p)[i]);
}

// output-channel interleave map: o in [0,512) -> packed n
__device__ __forceinline__ int omap(int o) {
    int half = o >> 8, d = o & 255;
    return ((d >> 4) * 32) + half * 16 + (d & 15);
}
// inverse: n -> o
__device__ __forceinline__ int omap_inv(int n) {
    int grp = n >> 5, half = (n >> 4) & 1, dlow = n & 15;
    return half * 256 + grp * 16 + dlow;
}

// ---------------------------------------------------------------- dtype detect
__global__ void k_detect(const void* sample, int* flag) {
    __shared__ int s;
    int t = threadIdx.x;
    if (t == 0) s = 0;
    __syncthreads();
    const unsigned short* u = (const unsigned short*)sample;
    float a = fabsf(b2f(u[2 * t]));
    if (!(a < 1e3f)) atomicOr(&s, 1);
    __syncthreads();
    if (t == 0) *flag = s;
}

// ---------------------------------------------------------------- embed + mask
__global__ __launch_bounds__(256)
void k_embed(const int* __restrict__ ids_c, const int* __restrict__ ids_w,
             const int* __restrict__ ids_p,
             const void* __restrict__ char_t,
             const void* __restrict__ word_t,
             const void* __restrict__ pos_t,
             unsigned short* __restrict__ embed,
             float* __restrict__ maskf,
             void* __restrict__ outv,
             const int* __restrict__ flag) {
    const int f32 = *flag;
    const int t = threadIdx.x;
    const int pos = blockIdx.x * 4 + (t >> 6);
    const int ch0 = (t & 63) * 8;
    const int c = ids_c[pos], w = ids_w[pos], p = ids_p[pos];
    if ((t & 63) == 0) {
        float m = (c != 0) ? 1.f : 0.f;
        maskf[pos] = m;
        size_t eidx = 65536 + 3276800 + (size_t)pos;
        if (f32) ((float*)outv)[eidx] = m;
        else ((unsigned short*)outv)[eidx] = f2b(m);
    }
    float tab[8], pe[8];
    const int in_char = (ch0 < 256);
    const size_t tidx = in_char ? ((size_t)c * 256 + ch0) : ((size_t)w * 256 + (ch0 - 256));
    const void* tp = in_char ? char_t : word_t;
    if (f32) {
        const float4 a0 = *(const float4*)((const float*)tp + tidx);
        const float4 a1 = *(const float4*)((const float*)tp + tidx + 4);
        tab[0]=a0.x; tab[1]=a0.y; tab[2]=a0.z; tab[3]=a0.w;
        tab[4]=a1.x; tab[5]=a1.y; tab[6]=a1.z; tab[7]=a1.w;
        const float4 b0 = *(const float4*)((const float*)pos_t + (size_t)p * 512 + ch0);
        const float4 b1 = *(const float4*)((const float*)pos_t + (size_t)p * 512 + ch0 + 4);
        pe[0]=b0.x; pe[1]=b0.y; pe[2]=b0.z; pe[3]=b0.w;
        pe[4]=b1.x; pe[5]=b1.y; pe[6]=b1.z; pe[7]=b1.w;
    } else {
        const unsigned short* tu = (const unsigned short*)tp + tidx;
        const unsigned short* pu = (const unsigned short*)pos_t + (size_t)p * 512 + ch0;
        uint4 av = *(const uint4*)tu;
        uint4 bv = *(const uint4*)pu;
        const unsigned short* as = (const unsigned short*)&av;
        const unsigned short* bs = (const unsigned short*)&bv;
#pragma unroll
        for (int i = 0; i < 8; ++i) { tab[i] = b2f(as[i]); pe[i] = b2f(bs[i]); }
    }
    unsigned short o[8];
#pragma unroll
    for (int i = 0; i < 8; ++i) o[i] = f2b(tab[i] + pe[i]);
    *(uint4*)(embed + (size_t)pos * 512 + ch0) = *(uint4*)o;
}

// ---------------------------------------------------------------- weight repack
__global__ void k_repack(const void* __restrict__ w1,
                         const void* __restrict__ w11,
                         const void* __restrict__ b1,
                         const void* __restrict__ b11,
                         unsigned short* __restrict__ w1p,
                         unsigned short* __restrict__ wp,
                         float* __restrict__ biasP,
                         const int* __restrict__ flag) {
    const int f32 = *flag;
    const int T1 = 3 * 512 * 512 / 8;
    const int T2 = 11 * 3 * 512 * 256 / 8;
    const int T3 = 12 * 512;
    const int total = T1 + T2 + T3;
    for (int idx = blockIdx.x * blockDim.x + threadIdx.x; idx < total;
         idx += gridDim.x * blockDim.x) {
        if (idx < T1) {
            int row = idx >> 6;
            int c0 = (idx & 63) * 8;
            int tap = row >> 9, n = row & 511;
            int o = omap_inv(n);
            unsigned short v[8];
#pragma unroll
            for (int i = 0; i < 8; ++i)
                v[i] = f2b(ldany(w1, (size_t)tap * 262144 + (size_t)(c0 + i) * 512 + o, f32));
            *(uint4*)(w1p + ((size_t)row << 9) + c0) = *(uint4*)v;
        } else if (idx < T1 + T2) {
            int j = idx - T1;
            int row = j >> 5;
            int c0 = (j & 31) * 8;
            int lt = row >> 9, n = row & 511;
            int o = omap_inv(n);
            unsigned short v[8];
#pragma unroll
            for (int i = 0; i < 8; ++i)
                v[i] = f2b(ldany(w11, (size_t)lt * 131072 + (size_t)(c0 + i) * 512 + o, f32));
            *(uint4*)(wp + ((size_t)row << 8) + c0) = *(uint4*)v;
        } else {
            int j = idx - T1 - T2;
            if (j < 512) {
                biasP[omap(j)] = ldany(b1, j, f32);
            } else {
                int jj = j - 512;
                int lay = jj >> 9, o = jj & 511;
                biasP[512 + lay * 512 + omap(o)] = ldany(b11, jj, f32);
            }
        }
    }
}

// ---------------------------------------------------------------- gated dilated conv layer
// BK=32, 2 barriers per k0: one stage phase writes the A-halo tile AND all
// three taps' B tiles, then 48 MFMA. LDS 33.4 KB -> 4 blocks/CU. XOR-swizzle
// q^(row&3) on 64B rows: staging conflict-free, frag reads <=2-way (free).
// NO register prefetch (R5 spilled: 400MB scratch writes).
template <int CIN, bool RES>
__global__ __launch_bounds__(256, 2)
void k_dgc(const unsigned short* __restrict__ xin,
           const unsigned short* __restrict__ wT,
           const float* __restrict__ bias,
           const float* __restrict__ maskf,
           unsigned short* __restrict__ xout,
           int dil) {
    __shared__ unsigned short ldsA[138 * 32];       //  8832 B (halo rows)
    __shared__ unsigned short ldsB[3 * 128 * 32];   // 24576 B
    const int id = blockIdx.x;
    const int xcd = id & 7, sl = id >> 3;
    const int mt = xcd * 32 + (sl >> 2);            // same-mt blocks share an XCD
    const int nt = sl & 3;
    const int m0 = mt * 128, n0 = nt * 128;
    const int b = m0 >> 9, s0 = m0 & 511;
    const int t = threadIdx.x;
    const int lane = t & 63, wv = t >> 6;
    const int wm = wv >> 1, wn = wv & 1;
    const int lm = lane & 15, lq = lane >> 4;
    const int NR = 128 + 2 * dil;

    f32x4 acc[4][4];
#pragma unroll
    for (int i = 0; i < 4; i++)
#pragma unroll
        for (int j = 0; j < 4; j++)
#pragma unroll
            for (int e = 0; e < 4; e++) acc[i][j][e] = 0.f;

    const unsigned short* xbase = xin + (size_t)b * S_ * CIN;

    for (int k0 = 0; k0 < CIN; k0 += 32) {
        __syncthreads();
        // stage A halo: NR*4 chunks (rows s0-dil .. s0+127+dil, 32 k-shorts)
        for (int i = t; i < NR * 4; i += 256) {
            int row = i >> 2, q = i & 3;
            int sp = s0 - dil + row;
            uint4 va = make_uint4(0u, 0u, 0u, 0u);
            if (sp >= 0 && sp < S_)
                va = *(const uint4*)(xbase + (size_t)sp * CIN + k0 + q * 8);
            *(uint4*)(ldsA + row * 32 + ((q ^ (row & 3)) * 8)) = va;
        }
        // stage B all taps: 1536 chunks, 6 per thread
#pragma unroll
        for (int i0 = 0; i0 < 6; ++i0) {
            int i = t + i0 * 256;
            int tap = i >> 9, rem = i & 511;
            int row = rem >> 2, q = rem & 3;
            uint4 vb = *(const uint4*)(wT + ((size_t)tap * 512 + n0 + row) * CIN + k0 + q * 8);
            *(uint4*)(ldsB + (tap * 128 + row) * 32 + ((q ^ (row & 3)) * 8)) = vb;
        }
        __syncthreads();
#pragma unroll
        for (int tap = 0; tap < 3; ++tap) {
            bf16x8 af[4], bfr[4];
#pragma unroll
            for (int mi = 0; mi < 4; ++mi) {
                const int er = wm * 64 + mi * 16 + lm + tap * dil;
                af[mi] = *(const bf16x8*)(ldsA + er * 32 + ((lq ^ (er & 3)) * 8));
            }
#pragma unroll
            for (int ni = 0; ni < 4; ++ni) {
                const int br = wn * 64 + ni * 16 + lm;
                bfr[ni] = *(const bf16x8*)(ldsB + (tap * 128 + br) * 32 + ((lq ^ (br & 3)) * 8));
            }
#pragma unroll
            for (int mi = 0; mi < 4; ++mi)
#pragma unroll
                for (int ni = 0; ni < 4; ++ni)
                    acc[mi][ni] = __builtin_amdgcn_mfma_f32_16x16x32_bf16(
                        af[mi], bfr[ni], acc[mi][ni], 0, 0, 0);
        }
    }

    // epilogue: ni pairs (2p, 2p+1) = (gate, value) blocks of same d-group
    const int colbase = n0 + wn * 64;
#pragma unroll
    for (int mi = 0; mi < 4; ++mi) {
#pragma unroll
        for (int p = 0; p < 2; ++p) {
            const int d = (colbase >> 1) + p * 16 + lm;
            const int ng = colbase + p * 32 + lm;
            const float bg = bias[ng], bv = bias[ng + 16];
#pragma unroll
            for (int r = 0; r < 4; ++r) {
                const int m = m0 + wm * 64 + mi * 16 + lq * 4 + r;
                float hg = acc[mi][2 * p][r] + bg;
                float hv = acc[mi][2 * p + 1][r] + bv;
                float g = sigm(hg);
                float o = hv * g;
                if (RES) {
                    float xi = b2f(xin[(size_t)m * CIN + d]);
                    o = xi * (1.f - g) + hv * g;
                }
                o *= maskf[m];
                xout[(size_t)m * 256 + d] = f2b(o);
            }
        }
    }
}

// ---------------------------------------------------------------- gather vec
__global__ void k_vec(const unsigned short* __restrict__ x, const int* __restrict__ loc,
                      float* __restrict__ vec) {
    int b = blockIdx.x;
    int j = threadIdx.x;
    int which = j >> 8, d = j & 255;
    int s = loc[b * 2 + which];
    vec[b * 512 + j] = b2f(x[((size_t)(b * 512 + s)) * 256 + d]);
}

// ---------------------------------------------------------------- BN stats over x
__global__ void k_zero(float* __restrict__ stats) { stats[threadIdx.x] = 0.f; }

__global__ void k_stats(const unsigned short* __restrict__ x, float* __restrict__ stats) {
    int c = threadIdx.x;
    int base = blockIdx.x * 128;
    float s = 0.f, q = 0.f;
    for (int r = 0; r < 128; ++r) {
        float v = b2f(x[(size_t)(base + r) * 256 + c]);
        s += v; q += v * v;
    }
    atomicAdd(&stats[c], s);
    atomicAdd(&stats[256 + c], q);
}

// ---------------------------------------------------------------- BN scale/shift
__global__ void k_final(const float* __restrict__ stats, const float* __restrict__ vec,
                        const void* __restrict__ gamma,
                        const void* __restrict__ beta,
                        float* __restrict__ scale, float* __restrict__ shift,
                        const int* __restrict__ flag) {
    const int f32 = *flag;
    int f = threadIdx.x;
    float mu, var;
    if (f < 256) {
        mu = stats[f] * (1.f / 32768.f);
        var = stats[256 + f] * (1.f / 32768.f) - mu * mu;
    } else {
        float s = 0.f, q = 0.f;
        int j = f - 256;
        for (int b = 0; b < 64; ++b) {
            float v = vec[b * 512 + j];
            s += v; q += v * v;
        }
        mu = s * (1.f / 64.f);
        var = q * (1.f / 64.f) - mu * mu;
    }
    float sc = ldany(gamma, f, f32) * rsqrtf(var + 1e-3f);
    scale[f] = sc;
    shift[f] = ldany(beta, f, f32) - mu * sc;
}

// ---------------------------------------------------------------- projection weight prep
__global__ void k_prep1(const float* __restrict__ scale, const void* __restrict__ po_w,
                        const void* __restrict__ sub_w,
                        unsigned short* __restrict__ pwT,
                        const int* __restrict__ flag) {
    const int f32 = *flag;
    int idx = blockIdx.x * blockDim.x + threadIdx.x;
    int n = idx >> 8, k = idx & 255;
    float v = 0.f;
    if (n < 100) v = scale[k] * ldany(po_w, (size_t)k * 100 + n, f32);
    else if (n < 102) v = ldany(sub_w, (size_t)k * 2 + (n - 100), f32);
    pwT[n * 256 + k] = f2b(v);
}

// ---------------------------------------------------------------- Cmat: wave-per-(b,n)
__global__ __launch_bounds__(256)
void k_cmat(const float* __restrict__ scale, const float* __restrict__ shift,
            const float* __restrict__ vec,
            const void* __restrict__ po_w,
            const void* __restrict__ po_b,
            const void* __restrict__ sub_b,
            float* __restrict__ Cmat,
            const int* __restrict__ flag) {
    const int f32 = *flag;
    const int wid = blockIdx.x * 4 + (threadIdx.x >> 6);
    const int lane = threadIdx.x & 63;
    const int b = wid / 102, n = wid - b * 102;
    if (b >= 64) return;
    if (n >= 100) {
        if (lane == 0) Cmat[b * 128 + n] = ldany(sub_b, n - 100, f32);
        return;
    }
    float partial = 0.f;
#pragma unroll
    for (int f = lane; f < 768; f += 64) {
        float term = shift[f];
        if (f >= 256) term += vec[b * 512 + (f - 256)] * scale[f];
        partial += term * ldany(po_w, (size_t)f * 100 + n, f32);
    }
#pragma unroll
    for (int off = 32; off > 0; off >>= 1)
        partial += __shfl_xor(partial, off);
    if (lane == 0) Cmat[b * 128 + n] = partial + ldany(po_b, n, f32);
}

// ---------------------------------------------------------------- final GEMM
__global__ __launch_bounds__(256)
void k_po(const unsigned short* __restrict__ x,
          const unsigned short* __restrict__ pwT,
          const float* __restrict__ Cmat,
          void* __restrict__ outv,
          const int* __restrict__ flag) {
    const int f32 = *flag;
    __shared__ unsigned short ldsA[128 * 40];
    __shared__ unsigned short ldsB[128 * 40];
    const int mt = blockIdx.x;
    const int m0 = mt * 128;
    const int b = m0 >> 9;
    const int t = threadIdx.x;
    const int lane = t & 63, wv = t >> 6;
    const int wm = wv >> 1, wn = wv & 1;
    const int lm = lane & 15, lq = lane >> 4;

    f32x4 acc[4][4];
#pragma unroll
    for (int i = 0; i < 4; i++)
#pragma unroll
        for (int j = 0; j < 4; j++)
#pragma unroll
            for (int e = 0; e < 4; e++) acc[i][j][e] = 0.f;

    for (int k0 = 0; k0 < 256; k0 += 32) {
        __syncthreads();
#pragma unroll
        for (int a0 = 0; a0 < 2; ++a0) {
            int a = t + a0 * 256;
            int row = a >> 2, q = a & 3;
            uint4 va = *(const uint4*)(x + (size_t)(m0 + row) * 256 + k0 + q * 8);
            *(uint4*)(ldsA + row * 40 + q * 8) = va;
            uint4 vb = *(const uint4*)(pwT + (size_t)row * 256 + k0 + q * 8);
            *(uint4*)(ldsB + row * 40 + q * 8) = vb;
        }
        __syncthreads();
        bf16x8 af[4], bfr[4];
#pragma unroll
        for (int mi = 0; mi < 4; ++mi)
            af[mi] = *(const bf16x8*)(ldsA + (wm * 64 + mi * 16 + lm) * 40 + lq * 8);
#pragma unroll
        for (int ni = 0; ni < 4; ++ni)
            bfr[ni] = *(const bf16x8*)(ldsB + (wn * 64 + ni * 16 + lm) * 40 + lq * 8);
#pragma unroll
        for (int mi = 0; mi < 4; ++mi)
#pragma unroll
            for (int ni = 0; ni < 4; ++ni)
                acc[mi][ni] = __builtin_amdgcn_mfma_f32_16x16x32_bf16(
                    af[mi], bfr[ni], acc[mi][ni], 0, 0, 0);
    }

#pragma unroll
    for (int mi = 0; mi < 4; ++mi)
#pragma unroll
        for (int ni = 0; ni < 4; ++ni) {
            const int n = wn * 64 + ni * 16 + lm;
            const float cc = Cmat[b * 128 + n];
#pragma unroll
            for (int r = 0; r < 4; ++r) {
                const int m = m0 + wm * 64 + mi * 16 + lq * 4 + r;
                const int s = m & 511;
                float v = sigm(acc[mi][ni][r] + cc);
                if (n < 102) {
                    size_t eidx;
                    if (n < 100) eidx = 65536 + (((size_t)b * 100 + n) * 512 + s);
                    else eidx = ((size_t)b * 2 + (n - 100)) * 512 + s;
                    if (f32) ((float*)outv)[eidx] = v;
                    else ((unsigned short*)outv)[eidx] = f2b(v);
                }
            }
        }
}

// ---------------------------------------------------------------- launch
extern "C" void kernel_launch(void* const* d_in, const int* in_sizes, int n_in,
                              void* d_out, int out_size, void* d_ws, size_t ws_size,
                              hipStream_t stream) {
    const int* ids_c = (const int*)d_in[0];
    const int* ids_w = (const int*)d_in[1];
    const int* ids_p = (const int*)d_in[2];
    const int* loc = (const int*)d_in[3];
    const void* char_t = d_in[4];
    const void* word_t = d_in[5];
    const void* pos_t = d_in[6];
    const void* w1 = d_in[7];
    const void* b1 = d_in[8];
    const void* w11 = d_in[9];
    const void* b11 = d_in[10];
    const void* sub_w = d_in[11];
    const void* sub_b = d_in[12];
    const void* po_w = d_in[13];
    const void* po_b = d_in[14];
    const void* gamma = d_in[15];
    const void* beta = d_in[16];

    char* ws = (char*)d_ws;
    unsigned short* embed = (unsigned short*)(ws + 0);
    unsigned short* xA = (unsigned short*)(ws + 33554432);
    unsigned short* xB = (unsigned short*)(ws + 50331648);
    unsigned short* w1p = (unsigned short*)(ws + 67108864);
    unsigned short* wp = (unsigned short*)(ws + 68681728);
    float* biasP = (float*)(ws + 77332480);
    float* maskf = (float*)(ws + 77357056);
    float* vec = (float*)(ws + 77488128);
    float* stats = (float*)(ws + 77619200);
    float* scale = (float*)(ws + 77621248);
    float* shift = (float*)(ws + 77624320);
    unsigned short* pwT = (unsigned short*)(ws + 77627392);
    float* Cmat = (float*)(ws + 77692928);
    int* dflag = (int*)(ws + 77725696);

    k_detect<<<1, 256, 0, stream>>>(word_t, dflag);
    k_zero<<<1, 512, 0, stream>>>(stats);
    k_embed<<<8192, 256, 0, stream>>>(ids_c, ids_w, ids_p, char_t, word_t, pos_t,
                                      embed, maskf, d_out, dflag);
    k_repack<<<2560, 256, 0, stream>>>(w1, w11, b1, b11, w1p, wp, biasP, dflag);

    k_dgc<512, false><<<1024, 256, 0, stream>>>(embed, w1p, biasP, maskf, xA, 1);

    const int dils[12] = {1, 2, 5, 1, 2, 5, 1, 2, 5, 1, 1, 1};
    unsigned short* xi = xA;
    unsigned short* xo = xB;
    for (int i = 1; i < 12; ++i) {
        k_dgc<256, true><<<1024, 256, 0, stream>>>(
            xi, wp + (size_t)(i - 1) * 3 * 512 * 256, biasP + i * 512, maskf, xo, dils[i]);
        unsigned short* tmp = xi; xi = xo; xo = tmp;
    }

    k_vec<<<64, 512, 0, stream>>>(xi, loc, vec);
    k_stats<<<256, 256, 0, stream>>>(xi, stats);
    k_final<<<1, 768, 0, stream>>>(stats, vec, gamma, beta, scale, shift, dflag);
    k_prep1<<<128, 256, 0, stream>>>(scale, po_w, sub_w, pwT, dflag);
    k_cmat<<<1632, 256, 0, stream>>>(scale, shift, vec, po_w, po_b, sub_b, Cmat, dflag);
    k_po<<<256, 256, 0, stream>>>(xi, pwT, Cmat, d_out, dflag);
}